// Round 2
// baseline (133.649 us; speedup 1.0000x reference)
//
#include <hip/hip_runtime.h>
#include <stdint.h>

// ModulatedConv2D: B=8, IC=OC=512, K=3, H=W=32
// 3 dispatches: style (sm, sm2), prep (Wtf repack + dpart demod partials +
// xsp repack), conv (implicit GEMM, 32x32x16 f16 MFMA, grid x=by so all
// blocks sharing a weight by-slice land on one XCD -> A is L2-resident).
//
// R2 change: R1's named-array double buffer (aA/aB) was still coalesced to
// 104 VGPR -- the pre-RA scheduler SANK the prefetch loads below the MFMA
// cluster (no dependency), then regalloc merged the buffers. Fix: a single
// __builtin_amdgcn_sched_barrier(0) between the prefetch-issue cluster and
// the MFMA cluster. Loads now must issue before compute; latency hides
// under the 36 MFMAs; both buffers stay live (VGPR should rise to ~176).

#define B_   8
#define IC_  512
#define OC_  512

static constexpr float RC_DENSE = 0.04419417382415922f;   // 1/sqrt(512)
static constexpr float RC_CONV  = 0.014731391274719739f;  // 1/sqrt(4608)

typedef _Float16 half8    __attribute__((ext_vector_type(8)));
typedef float    floatx16 __attribute__((ext_vector_type(16)));

// async global->LDS, 16B per lane; LDS dest = wave-uniform base + lane*16
__device__ __forceinline__ void g2l(const void* g, void* l) {
  __builtin_amdgcn_global_load_lds(
      (const __attribute__((address_space(1))) void*)g,
      (__attribute__((address_space(3))) void*)l, 16, 0, 0);
}

// ---- sm = (w@(RC_DENSE*dw) + db + 1)*RC_CONV ; sm2 = sm^2 ----
__global__ __launch_bounds__(256) void style_kernel(
    const float* __restrict__ wv, const float* __restrict__ dw,
    const float* __restrict__ db, float* __restrict__ sm,
    float* __restrict__ sm2) {
  const int b = blockIdx.y;
  const int i = blockIdx.x * 64 + (threadIdx.x & 63);
  const int jg = threadIdx.x >> 6;
  __shared__ float red[4][64];
  float p = 0.f;
  for (int j = jg * 128; j < jg * 128 + 128; ++j)
    p += wv[b * IC_ + j] * dw[(size_t)j * IC_ + i];
  red[jg][threadIdx.x & 63] = p;
  __syncthreads();
  if (threadIdx.x < 64) {
    float s = red[0][threadIdx.x] + red[1][threadIdx.x] +
              red[2][threadIdx.x] + red[3][threadIdx.x];
    s = s * RC_DENSE + db[i] + 1.0f;
    float v = s * RC_CONV;
    sm[b * IC_ + i] = v;
    sm2[b * IC_ + i] = v * v;
  }
}

// ---------------- prep: 512 blocks (2/CU) ----------------
// bid<256 (wts role): 32oc x 32ic half-tile; Wtf[by][icb][ktq 36][oc64][8] f16
//   + dpart[icb][b][oc] = sum_icl sm2 * sum_t cw^2 (disjoint oc, no atomics)
// bid>=256 (xsp role): per (b,h) row; xsp[b][icb][r34][kk2][kq2][C34][8] f16
__global__ __launch_bounds__(256) void prep_kernel(
    const float* __restrict__ cw, const float* __restrict__ x,
    const float* __restrict__ sm, const float* __restrict__ sm2,
    _Float16* __restrict__ Wtf, float* __restrict__ dpart,
    _Float16* __restrict__ xsp) {
  __shared__ __align__(16) char smem[33280];
  const int bid = blockIdx.x;
  const int tid = threadIdx.x;
  if (bid < 256) {
    // ---------------- wts + dpart role ----------------
    _Float16* LA = (_Float16*)smem;                // 18432 B
    float* redall = (float*)(smem + 18432);        // 8192 B (8b x 8g x 32oc)
    const int by2 = bid >> 4, icb = bid & 15;
    const int by = by2 >> 1, h2 = by2 & 1;
    const int oc0 = by * 64 + h2 * 32, ic0 = icb * 32;
    const int ocl = tid & 31, g = tid >> 5;        // g 0..7
    float sq4[4] = {};
    for (int m = 0; m < 36; ++m) {
      int r = m * 8 + g;                 // r = t*32+icl; t=m>>2, icl=8*(m&3)+g
      int t = r >> 5, icl = r & 31;
      float v = cw[(size_t)(t * IC_ + ic0 + icl) * OC_ + oc0 + ocl];  // 128B seg
      sq4[m & 3] += v * v;
      LA[m * 256 + ocl * 8 + g] = (_Float16)v;     // ktq == m, j == g
    }
    for (int b = 0; b < 8; ++b) {
      float p = 0.f;
      for (int s = 0; s < 4; ++s)
        p += sm2[b * IC_ + ic0 + g + 8 * s] * sq4[s];
      redall[(b * 8 + g) * 32 + ocl] = p;
    }
    __syncthreads();
    // Wtf: 1152 contiguous-per-wave b128 chunks
    _Float16* dst = Wtf + (size_t)(by * 16 + icb) * 18432;
    for (int it = 0; it < 5; ++it) {
      int c = it * 256 + tid;
      if (c < 1152) {
        int m = c >> 5, o2 = c & 31;
        *(half8*)(dst + (size_t)(m * 64 + h2 * 32 + o2) * 8) =
            *(const half8*)&LA[m * 256 + o2 * 8];
      }
    }
    // dpart: reduce over g
    const int bb = tid >> 5, o3 = tid & 31;
    float s = 0.f;
    for (int g2 = 0; g2 < 8; ++g2) s += redall[(bb * 8 + g2) * 32 + o3];
    dpart[(size_t)icb * 4096 + bb * OC_ + oc0 + o3] = s;
  } else {
    // ---------------- xsp role (R4-proven structure) ----------------
    _Float16* Xt = (_Float16*)smem;                // 32*520*2 = 33280 B
    const int rb = bid - 256;
    const int b = rb >> 5, h = rb & 31;
    for (int k = 0; k < 16; ++k) {
      int idx = k * 256 + tid;           // 512 ic * 8 w-quads
      int ic = idx >> 3, wc = (idx & 7) * 4;
      float4 v = *(const float4*)&x[((size_t)(b * IC_ + ic) * 32 + h) * 32 + wc];
      float s = sm[b * IC_ + ic];
      Xt[(wc + 0) * 520 + ic] = (_Float16)(v.x * s);
      Xt[(wc + 1) * 520 + ic] = (_Float16)(v.y * s);
      Xt[(wc + 2) * 520 + ic] = (_Float16)(v.z * s);
      Xt[(wc + 3) * 520 + ic] = (_Float16)(v.w * s);
    }
    __syncthreads();
    _Float16* xb = xsp + (size_t)b * 16 * 36992;
    const int r = h + 1;
    half8 z = {};
    for (int it = 0; it < 9; ++it) {     // 16 icb * 4 kkq * 34 C = 2176 chunks
      int c = it * 256 + tid;
      if (c < 2176) {
        int icb = c / 136, rem = c - 136 * icb, kkq = rem / 34, C = rem - 34 * kkq;
        half8 val = z;
        if (C != 0 && C != 33)
          val = *(const half8*)&Xt[(C - 1) * 520 + icb * 32 + kkq * 8];
        *(half8*)&xb[(size_t)icb * 36992 + (size_t)r * 1088 + kkq * 272 + C * 8] = val;
      }
    }
    if (h == 0 || h == 31) {             // zero top/bottom padded rows
      const int rz = (h == 0) ? 0 : 33;
      for (int it = 0; it < 9; ++it) {
        int c = it * 256 + tid;
        if (c < 2176) {
          int icb = c / 136, rem = c - 136 * icb, kkq = rem / 34, C = rem - 34 * kkq;
          *(half8*)&xb[(size_t)icb * 36992 + (size_t)rz * 1088 + kkq * 272 + C * 8] = z;
        }
      }
    }
  }
}

// ---- conv: block 64oc x 128px (4 rows), grid (by 8, bx 8, b 8) = 512 ----
// gridDim.x == 8 and x == by  =>  XCD = linear_id % 8 = by: all 64 blocks
// sharing a by weight-slice (590 KB) run on one XCD -> A reads hit L2.
// Wave (wm,wn): 32oc x 64px (2 rows), acc[2]x16.
// A-fragment double-buffer aA/aB with a sched_barrier(0) fence between the
// prefetch-issue cluster and the MFMA cluster (prevents load sinking).

#define CONV_COMPUTE(ACUR)                                                   \
    _Pragma("unroll")                                                        \
    for (int s = 0; s < 4; ++s) {                                            \
      _Pragma("unroll")                                                      \
      for (int kw = 0; kw < 3; ++kw) {                                       \
        _Pragma("unroll")                                                    \
        for (int kk = 0; kk < 2; ++kk) {                                     \
          half8 xv = *(const half8*)(Xp + s * 1088 + kk * 544 + kw * 8);     \
          _Pragma("unroll")                                                  \
          for (int kh = 0; kh < 3; ++kh) {                                   \
            int j = s - kh;                                                  \
            if (j >= 0 && j < 2)                                             \
              acc[j] = __builtin_amdgcn_mfma_f32_32x32x16_f16(               \
                  ACUR[kh * 3 + kw][kk], xv, acc[j], 0, 0, 0);               \
          }                                                                  \
        }                                                                    \
      }                                                                      \
    }

#define CONV_STEP(ICB, CUR, ACUR, ANXT)                                      \
  {                                                                          \
    __syncthreads();                                                         \
    if ((ICB) + 1 < 16) {                                                    \
      const _Float16* gA1 = gA + (size_t)((ICB) + 1) * 18432 + aoff;         \
      _Pragma("unroll")                                                      \
      for (int t = 0; t < 9; ++t) {                                          \
        ANXT[t][0] = *(const half8*)(gA1 + (t * 2 + 0) * 1024);              \
        ANXT[t][1] = *(const half8*)(gA1 + (t * 2 + 1) * 1024);              \
      }                                                                      \
      const _Float16* gX1 = gX + (size_t)((ICB) + 1) * 36992;                \
      for (int i = 0; i < 4; ++i) {                                          \
        int c = i * 256 + tid;                                               \
        if (c < 816) g2l(gX1 + (size_t)c * 8, &Xb[(CUR) ^ 1][c * 8]);        \
      }                                                                      \
    }                                                                        \
    /* hard fence: prefetch loads may NOT sink below this point */           \
    __builtin_amdgcn_sched_barrier(0);                                       \
    const _Float16* Xp = &Xb[(CUR)][0] + (wn * 2) * 1088 + kq * 272 + n * 8; \
    CONV_COMPUTE(ACUR)                                                       \
  }

__global__ __launch_bounds__(256, 2) void conv_kernel(
    const _Float16* __restrict__ Wtf,   // [8 by][16 icb][36 ktq][64 oc][8]
    const _Float16* __restrict__ xsp,   // [8 b][16 icb][34 r][2 kk][2 kq][34 C][8]
    const float* __restrict__ dpart,    // [16 icb][8 b][512 oc]
    float* __restrict__ out) {          // [8][512][32][32]
  const int by = blockIdx.x, bx = blockIdx.y, b = blockIdx.z;
  const int tid = threadIdx.x, lane = tid & 63, w = tid >> 6;
  const int wm = w & 1, wn = w >> 1;    // wn: which 2-row half
  const int n = lane & 31, kq = lane >> 5;
  const int h0 = bx * 4;                // output rows h0..h0+3; padded h0..h0+5

  __shared__ _Float16 Xb[2][6528];      // 816 chunks x 8 halfs = 13056 B each
  __shared__ float redd[4][64];
  __shared__ float dvl[64];

  const _Float16* gX = xsp + (size_t)b * 16 * 36992 + (size_t)h0 * 1088;
  const _Float16* gA = Wtf + (size_t)(by * 16) * 18432;
  const int aoff = kq * 512 + (wm * 32 + n) * 8;

  // prologue: stage X(0), load A(0) into aA
  for (int i = 0; i < 4; ++i) {
    int c = i * 256 + tid;
    if (c < 816) g2l(gX + (size_t)c * 8, &Xb[0][c * 8]);
  }
  half8 aA[9][2], aB[9][2];
#pragma unroll
  for (int t = 0; t < 9; ++t) {
    aA[t][0] = *(const half8*)(gA + aoff + (t * 2 + 0) * 1024);
    aA[t][1] = *(const half8*)(gA + aoff + (t * 2 + 1) * 1024);
  }

  floatx16 acc[2] = {};
  for (int ii = 0; ii < 16; ii += 2) {
    CONV_STEP(ii,     0, aA, aB)
    CONV_STEP(ii + 1, 1, aB, aA)
  }

  // epilogue: reduce dpart over 16 icb -> dv[64] in LDS, then plain stores
  __syncthreads();
  {
    const int oc_l = tid & 63, ig = tid >> 6;
    float s = 0.f;
    for (int k = 0; k < 4; ++k)
      s += dpart[(size_t)(ig * 4 + k) * 4096 + b * OC_ + by * 64 + oc_l];
    redd[ig][oc_l] = s;
  }
  __syncthreads();
  if (tid < 64)
    dvl[tid] = rsqrtf(redd[0][tid] + redd[1][tid] + redd[2][tid] +
                      redd[3][tid] + 1e-8f);
  __syncthreads();
  // D col(px)=n, row(oc)=(rg&3)+8*(rg>>2)+4*kq
  const int oc0 = by * 64 + wm * 32;
  const int r0 = h0 + wn * 2;
#pragma unroll
  for (int rg = 0; rg < 16; ++rg) {
    const int row = (rg & 3) + 8 * (rg >> 2) + 4 * kq;
    const float dv = dvl[wm * 32 + row];
    float* op = out + ((size_t)b * OC_ + oc0 + row) * 1024 + r0 * 32 + n;
    op[0]  = acc[0][rg] * dv;
    op[32] = acc[1][rg] * dv;
  }
}

extern "C" void kernel_launch(void* const* d_in, const int* in_sizes, int n_in,
                              void* d_out, int out_size, void* d_ws, size_t ws_size,
                              hipStream_t stream) {
  const float* x       = (const float*)d_in[0];
  const float* w       = (const float*)d_in[1];
  const float* conv_w  = (const float*)d_in[2];
  const float* dense_w = (const float*)d_in[3];
  const float* dense_b = (const float*)d_in[4];
  float* out = (float*)d_out;

  char* ws = (char*)d_ws;
  float*    sm    = (float*)ws;                        // 16 KB
  float*    sm2   = (float*)(ws + (16 << 10));         // 16 KB
  float*    dpart = (float*)(ws + (32 << 10));         // 256 KB
  _Float16* Wtf   = (_Float16*)(ws + (288 << 10));               // 4,718,592 B
  _Float16* xsp   = (_Float16*)(ws + (288 << 10) + 4718592);     // 9,469,952 B

  style_kernel<<<dim3(8, B_), 256, 0, stream>>>(w, dense_w, dense_b, sm, sm2);
  prep_kernel<<<512, 256, 0, stream>>>(conv_w, x, sm, sm2, Wtf, dpart, xsp);
  conv_kernel<<<dim3(8, 8, B_), 256, 0, stream>>>(Wtf, xsp, dpart, out);
}

// Round 3
// 130.250 us; speedup vs baseline: 1.0261x; 1.0261x over previous
//
#include <hip/hip_runtime.h>
#include <stdint.h>

// ModulatedConv2D: B=8, IC=OC=512, K=3, H=W=32
// 3 dispatches: style (sm, sm2), prep (Wtf repack + dpart demod partials +
// xsp repack), conv (implicit GEMM, 32x32x16 f16 MFMA, grid x=by so all
// blocks sharing a weight by-slice land on one XCD -> A is L2-resident).
//
// R3 change: register double-buffering of A was twice defeated by regalloc
// (VGPR stuck at 104 -> loads issue after last use, latency+BW fully
// exposed at the barrier drain). Structural fix: A now staged through LDS
// via global_load_lds (no VGPR dest -> issues at step top, hides under
// MFMAs; dedups the wn-pair duplication, halving A L2 traffic). K-loop
// split into 32 kk-half sub-steps so double-buffered A(18.4KB)+X(6.5KB)
// fits 2 blocks/CU (51.2 KB LDS/block). Waves read A via ds_read_b128
// (conflict-free stride-16, same class as X reads).

#define B_   8
#define IC_  512
#define OC_  512

static constexpr float RC_DENSE = 0.04419417382415922f;   // 1/sqrt(512)
static constexpr float RC_CONV  = 0.014731391274719739f;  // 1/sqrt(4608)

typedef _Float16 half8    __attribute__((ext_vector_type(8)));
typedef float    floatx16 __attribute__((ext_vector_type(16)));

// async global->LDS, 16B per lane; LDS dest = wave-uniform base + lane*16
__device__ __forceinline__ void g2l(const void* g, void* l) {
  __builtin_amdgcn_global_load_lds(
      (const __attribute__((address_space(1))) void*)g,
      (__attribute__((address_space(3))) void*)l, 16, 0, 0);
}

// ---- sm = (w@(RC_DENSE*dw) + db + 1)*RC_CONV ; sm2 = sm^2 ----
__global__ __launch_bounds__(256) void style_kernel(
    const float* __restrict__ wv, const float* __restrict__ dw,
    const float* __restrict__ db, float* __restrict__ sm,
    float* __restrict__ sm2) {
  const int b = blockIdx.y;
  const int i = blockIdx.x * 64 + (threadIdx.x & 63);
  const int jg = threadIdx.x >> 6;
  __shared__ float red[4][64];
  float p = 0.f;
  for (int j = jg * 128; j < jg * 128 + 128; ++j)
    p += wv[b * IC_ + j] * dw[(size_t)j * IC_ + i];
  red[jg][threadIdx.x & 63] = p;
  __syncthreads();
  if (threadIdx.x < 64) {
    float s = red[0][threadIdx.x] + red[1][threadIdx.x] +
              red[2][threadIdx.x] + red[3][threadIdx.x];
    s = s * RC_DENSE + db[i] + 1.0f;
    float v = s * RC_CONV;
    sm[b * IC_ + i] = v;
    sm2[b * IC_ + i] = v * v;
  }
}

// ---------------- prep: 512 blocks (2/CU) ----------------
// bid<256 (wts role): 32oc x 32ic half-tile; Wtf[by][icb][ktq 36][oc64][8] f16
//   + dpart[icb][b][oc] = sum_icl sm2 * sum_t cw^2 (disjoint oc, no atomics)
// bid>=256 (xsp role): per (b,h) row; xsp[b][icb][r34][kk2][kq2][C34][8] f16
__global__ __launch_bounds__(256) void prep_kernel(
    const float* __restrict__ cw, const float* __restrict__ x,
    const float* __restrict__ sm, const float* __restrict__ sm2,
    _Float16* __restrict__ Wtf, float* __restrict__ dpart,
    _Float16* __restrict__ xsp) {
  __shared__ __align__(16) char smem[33280];
  const int bid = blockIdx.x;
  const int tid = threadIdx.x;
  if (bid < 256) {
    // ---------------- wts + dpart role ----------------
    _Float16* LA = (_Float16*)smem;                // 18432 B
    float* redall = (float*)(smem + 18432);        // 8192 B (8b x 8g x 32oc)
    const int by2 = bid >> 4, icb = bid & 15;
    const int by = by2 >> 1, h2 = by2 & 1;
    const int oc0 = by * 64 + h2 * 32, ic0 = icb * 32;
    const int ocl = tid & 31, g = tid >> 5;        // g 0..7
    float sq4[4] = {};
    for (int m = 0; m < 36; ++m) {
      int r = m * 8 + g;                 // r = t*32+icl; t=m>>2, icl=8*(m&3)+g
      int t = r >> 5, icl = r & 31;
      float v = cw[(size_t)(t * IC_ + ic0 + icl) * OC_ + oc0 + ocl];  // 128B seg
      sq4[m & 3] += v * v;
      LA[m * 256 + ocl * 8 + g] = (_Float16)v;     // ktq == m, j == g
    }
    for (int b = 0; b < 8; ++b) {
      float p = 0.f;
      for (int s = 0; s < 4; ++s)
        p += sm2[b * IC_ + ic0 + g + 8 * s] * sq4[s];
      redall[(b * 8 + g) * 32 + ocl] = p;
    }
    __syncthreads();
    // Wtf: 1152 contiguous-per-wave b128 chunks
    _Float16* dst = Wtf + (size_t)(by * 16 + icb) * 18432;
    for (int it = 0; it < 5; ++it) {
      int c = it * 256 + tid;
      if (c < 1152) {
        int m = c >> 5, o2 = c & 31;
        *(half8*)(dst + (size_t)(m * 64 + h2 * 32 + o2) * 8) =
            *(const half8*)&LA[m * 256 + o2 * 8];
      }
    }
    // dpart: reduce over g
    const int bb = tid >> 5, o3 = tid & 31;
    float s = 0.f;
    for (int g2 = 0; g2 < 8; ++g2) s += redall[(bb * 8 + g2) * 32 + o3];
    dpart[(size_t)icb * 4096 + bb * OC_ + oc0 + o3] = s;
  } else {
    // ---------------- xsp role (R4-proven structure) ----------------
    _Float16* Xt = (_Float16*)smem;                // 32*520*2 = 33280 B
    const int rb = bid - 256;
    const int b = rb >> 5, h = rb & 31;
    for (int k = 0; k < 16; ++k) {
      int idx = k * 256 + tid;           // 512 ic * 8 w-quads
      int ic = idx >> 3, wc = (idx & 7) * 4;
      float4 v = *(const float4*)&x[((size_t)(b * IC_ + ic) * 32 + h) * 32 + wc];
      float s = sm[b * IC_ + ic];
      Xt[(wc + 0) * 520 + ic] = (_Float16)(v.x * s);
      Xt[(wc + 1) * 520 + ic] = (_Float16)(v.y * s);
      Xt[(wc + 2) * 520 + ic] = (_Float16)(v.z * s);
      Xt[(wc + 3) * 520 + ic] = (_Float16)(v.w * s);
    }
    __syncthreads();
    _Float16* xb = xsp + (size_t)b * 16 * 36992;
    const int r = h + 1;
    half8 z = {};
    for (int it = 0; it < 9; ++it) {     // 16 icb * 4 kkq * 34 C = 2176 chunks
      int c = it * 256 + tid;
      if (c < 2176) {
        int icb = c / 136, rem = c - 136 * icb, kkq = rem / 34, C = rem - 34 * kkq;
        half8 val = z;
        if (C != 0 && C != 33)
          val = *(const half8*)&Xt[(C - 1) * 520 + icb * 32 + kkq * 8];
        *(half8*)&xb[(size_t)icb * 36992 + (size_t)r * 1088 + kkq * 272 + C * 8] = val;
      }
    }
    if (h == 0 || h == 31) {             // zero top/bottom padded rows
      const int rz = (h == 0) ? 0 : 33;
      for (int it = 0; it < 9; ++it) {
        int c = it * 256 + tid;
        if (c < 2176) {
          int icb = c / 136, rem = c - 136 * icb, kkq = rem / 34, C = rem - 34 * kkq;
          *(half8*)&xb[(size_t)icb * 36992 + (size_t)rz * 1088 + kkq * 272 + C * 8] = z;
        }
      }
    }
  }
}

// ---- conv: block 64oc x 128px (4 rows), grid (by 8, bx 8, b 8) = 512 ----
// gridDim.x == 8 and x == by  =>  XCD = linear_id % 8 = by: all 64 blocks
// sharing a by weight-slice run on one XCD -> A reads hit that XCD's L2.
// K-loop: 32 sub-steps (icb 0..15 x kk 0..1). Per sub-step both A-half
// (18432 B) and X-half (6528 B) are staged to LDS via global_load_lds,
// double-buffered; one __syncthreads per sub-step (compiler emits the
// vmcnt(0) drain before s_barrier). Waves: (wm: oc half, wn: row pair),
// A frags via 9x ds_read_b128, X frags via 12x ds_read_b128, 18 MFMA.
__global__ __launch_bounds__(256, 2) void conv_kernel(
    const _Float16* __restrict__ Wtf,   // [8 by][16 icb][36 m][64 oc][8]
    const _Float16* __restrict__ xsp,   // [8 b][16 icb][34 r][2 kk][2 kq][34 C][8]
    const float* __restrict__ dpart,    // [16 icb][8 b][512 oc]
    float* __restrict__ out) {          // [8][512][32][32]
  const int by = blockIdx.x, bx = blockIdx.y, b = blockIdx.z;
  const int tid = threadIdx.x, lane = tid & 63, w = tid >> 6;
  const int wm = w & 1, wn = w >> 1;    // wn: which 2-row half
  const int n = lane & 31, kq = lane >> 5;
  const int h0 = bx * 4;                // output rows h0..h0+3; padded h0..h0+5

  // LDS: A halves [2][9 run][1024 halfs] + X halves [2][6 r][544 halfs]
  __shared__ __align__(16) _Float16 As[2][9216];   // 18432 B each
  __shared__ __align__(16) _Float16 Xs[2][3264];   //  6528 B each
  __shared__ float redd[4][64];
  __shared__ float dvl[64];

  const _Float16* gX = xsp + (size_t)b * 16 * 36992 + (size_t)h0 * 1088;
  const _Float16* gA = Wtf + (size_t)(by * 16) * 18432;

  // stage sub-step st into parity p.
  // A-half: m = t*4 + kk*2 + {0,1}: 9 runs of 2048 B; chunk c: r=c>>7, o=c&127
  //   src halfs = icb*18432 + r*2048 + kk*1024 + o*8 ; LDS = linear c*8
  // X-half: 6 rows x 544 halfs; chunk c: r=c/68, o=c%68
  //   src halfs = icb*36992 + r*1088 + kk*544 + o*8 ; LDS = linear c*8
  auto stage = [&](int st, int p) {
    const int icb = st >> 1, kk = st & 1;
    const _Float16* a = gA + (size_t)icb * 18432 + kk * 1024;
#pragma unroll
    for (int it = 0; it < 5; ++it) {
      int c = it * 256 + tid;
      if (c < 1152) {
        int r = c >> 7, o = c & 127;
        g2l(a + r * 2048 + o * 8, &As[p][c * 8]);
      }
    }
    const _Float16* xg = gX + (size_t)icb * 36992 + kk * 544;
#pragma unroll
    for (int it = 0; it < 2; ++it) {
      int c = it * 256 + tid;
      if (c < 408) {
        int r = c / 68, o = c - r * 68;
        g2l(xg + r * 1088 + o * 8, &Xs[p][c * 8]);
      }
    }
  };

  floatx16 acc[2] = {};
  stage(0, 0);
  for (int st = 0; st < 32; ++st) {
    const int cur = st & 1;
    __syncthreads();                    // buf[cur] staged & visible
    if (st + 1 < 32) stage(st + 1, cur ^ 1);
    const _Float16* Ap = &As[cur][0] + kq * 512 + (wm * 32 + n) * 8;
    const _Float16* Xp = &Xs[cur][0] + (wn * 2) * 544 + kq * 272 + n * 8;
    half8 a[9];
#pragma unroll
    for (int t = 0; t < 9; ++t) a[t] = *(const half8*)(Ap + t * 1024);
#pragma unroll
    for (int s = 0; s < 4; ++s) {
#pragma unroll
      for (int kw = 0; kw < 3; ++kw) {
        half8 xv = *(const half8*)(Xp + s * 544 + kw * 8);
#pragma unroll
        for (int kh = 0; kh < 3; ++kh) {
          int j = s - kh;
          if (j >= 0 && j < 2)
            acc[j] = __builtin_amdgcn_mfma_f32_32x32x16_f16(
                a[kh * 3 + kw], xv, acc[j], 0, 0, 0);
        }
      }
    }
  }

  // epilogue: reduce dpart over 16 icb -> dv[64] in LDS, then plain stores
  __syncthreads();
  {
    const int oc_l = tid & 63, ig = tid >> 6;
    float s = 0.f;
    for (int k = 0; k < 4; ++k)
      s += dpart[(size_t)(ig * 4 + k) * 4096 + b * OC_ + by * 64 + oc_l];
    redd[ig][oc_l] = s;
  }
  __syncthreads();
  if (tid < 64)
    dvl[tid] = rsqrtf(redd[0][tid] + redd[1][tid] + redd[2][tid] +
                      redd[3][tid] + 1e-8f);
  __syncthreads();
  // D col(px)=n, row(oc)=(rg&3)+8*(rg>>2)+4*kq
  const int oc0 = by * 64 + wm * 32;
  const int r0 = h0 + wn * 2;
#pragma unroll
  for (int rg = 0; rg < 16; ++rg) {
    const int row = (rg & 3) + 8 * (rg >> 2) + 4 * kq;
    const float dv = dvl[wm * 32 + row];
    float* op = out + ((size_t)b * OC_ + oc0 + row) * 1024 + r0 * 32 + n;
    op[0]  = acc[0][rg] * dv;
    op[32] = acc[1][rg] * dv;
  }
}

extern "C" void kernel_launch(void* const* d_in, const int* in_sizes, int n_in,
                              void* d_out, int out_size, void* d_ws, size_t ws_size,
                              hipStream_t stream) {
  const float* x       = (const float*)d_in[0];
  const float* w       = (const float*)d_in[1];
  const float* conv_w  = (const float*)d_in[2];
  const float* dense_w = (const float*)d_in[3];
  const float* dense_b = (const float*)d_in[4];
  float* out = (float*)d_out;

  char* ws = (char*)d_ws;
  float*    sm    = (float*)ws;                        // 16 KB
  float*    sm2   = (float*)(ws + (16 << 10));         // 16 KB
  float*    dpart = (float*)(ws + (32 << 10));         // 256 KB
  _Float16* Wtf   = (_Float16*)(ws + (288 << 10));               // 4,718,592 B
  _Float16* xsp   = (_Float16*)(ws + (288 << 10) + 4718592);     // 9,469,952 B

  style_kernel<<<dim3(8, B_), 256, 0, stream>>>(w, dense_w, dense_b, sm, sm2);
  prep_kernel<<<512, 256, 0, stream>>>(conv_w, x, sm, sm2, Wtf, dpart, xsp);
  conv_kernel<<<dim3(8, 8, B_), 256, 0, stream>>>(Wtf, xsp, dpart, out);
}